// Round 11
// baseline (448.038 us; speedup 1.0000x reference)
//
#include <hip/hip_runtime.h>

#define N_NODES 50000
#define N_EDGES 800000
#define N_GRAPHS 500
#define DH 128
#define OUT_STRIDE 384
#define BN_EPS 1e-5f
#define SCAN_NB ((N_NODES + 255) / 256)

typedef __attribute__((ext_vector_type(8))) short bf16x8;
typedef __attribute__((ext_vector_type(4))) float f32x4;

__device__ __forceinline__ float4 ld4(const float* p) { return *(const float4*)p; }
__device__ __forceinline__ void st4(float* p, float4 v) { *(float4*)p = v; }

__device__ __forceinline__ short f2bf(float f) {
    union { float f; unsigned u; } v; v.f = f;
    unsigned r = v.u + 0x7FFFu + ((v.u >> 16) & 1u);
    return (short)(r >> 16);
}
__device__ __forceinline__ float bu2f(unsigned short v) {
    union { unsigned u; float f; } x; x.u = ((unsigned)v) << 16; return x.f;
}
__device__ __forceinline__ float blo(int w) {
    union { unsigned u; float f; } x; x.u = ((unsigned)w) << 16; return x.f;
}
__device__ __forceinline__ float bhi(int w) {
    union { unsigned u; float f; } x; x.u = (unsigned)w & 0xFFFF0000u; return x.f;
}

// ---------------- fused prep: deg count (edge) + x->bf16[16] + graph bounds (node) ----------------
__global__ void prep_k(const int* __restrict__ dst, int* __restrict__ deg,
                       const float* __restrict__ x, unsigned short* __restrict__ xbf,
                       const int* __restrict__ batch, int* __restrict__ gstart,
                       int E, int n, int G) {
    int i = blockIdx.x * 256 + threadIdx.x;
    if (i < E) atomicAdd(&deg[dst[i]], 1);
    if (i < n) {
        const float* s = x + (size_t)i * 9;
        union { unsigned short u[16]; int4 v[2]; } o;
#pragma unroll
        for (int j = 0; j < 9; ++j) o.u[j] = (unsigned short)f2bf(s[j]);
#pragma unroll
        for (int j = 9; j < 16; ++j) o.u[j] = 0;
        int4* d = (int4*)(xbf + (size_t)i * 16);
        d[0] = o.v[0];
        d[1] = o.v[1];
        int b = batch[i];
        if (i == 0) {
            for (int g = 0; g <= b; ++g) gstart[g] = 0;
        } else {
            int p = batch[i - 1];
            for (int g = p + 1; g <= b; ++g) gstart[g] = i;
        }
        if (i == n - 1) {
            for (int g = b + 1; g <= G; ++g) gstart[g] = n;
        }
    }
}

// hierarchical scan
__global__ void deg_bsum_k(const int* __restrict__ deg, int* __restrict__ bsum, int n) {
    __shared__ int red[256];
    int t = threadIdx.x, i = blockIdx.x * 256 + t;
    red[t] = (i < n) ? deg[i] : 0;
    __syncthreads();
    for (int off = 128; off > 0; off >>= 1) {
        if (t < off) red[t] += red[t + off];
        __syncthreads();
    }
    if (t == 0) bsum[blockIdx.x] = red[0];
}

__global__ void bsum_scan_k(const int* __restrict__ bsum, int* __restrict__ boff,
                            int* __restrict__ rowstart, int nb, int n) {
    __shared__ int s[256];
    int t = threadIdx.x;
    int v = (t < nb) ? bsum[t] : 0;
    s[t] = v;
    __syncthreads();
    for (int off = 1; off < 256; off <<= 1) {
        int u = (t >= off) ? s[t - off] : 0;
        __syncthreads();
        s[t] += u;
        __syncthreads();
    }
    if (t < nb) boff[t] = s[t] - v;
    if (t == 255) rowstart[n] = s[255];
}

__global__ void deg_scan_k(const int* __restrict__ deg, const int* __restrict__ boff,
                           int* __restrict__ rowstart, int* __restrict__ cursor, int n) {
    __shared__ int s[256];
    int t = threadIdx.x, i = blockIdx.x * 256 + t;
    int v = (i < n) ? deg[i] : 0;
    s[t] = v;
    __syncthreads();
    for (int off = 1; off < 256; off <<= 1) {
        int u = (t >= off) ? s[t - off] : 0;
        __syncthreads();
        s[t] += u;
        __syncthreads();
    }
    if (i < n) {
        int r = boff[blockIdx.x] + s[t] - v;
        rowstart[i] = r;
        cursor[i] = r;
    }
}

// 16-byte adjacency record {src(int bits), e0, e1, e2 fp32}; one edge/thread.
// 16B store path measured faster than 8B (r10: 66us vs r8: 50us, same WRITE_SIZE).
__global__ void csr_fill_k(const int* __restrict__ src, const int* __restrict__ dst,
                           const float* __restrict__ ea, int* __restrict__ cursor,
                           float4* __restrict__ adj, int E) {
    int e = blockIdx.x * 256 + threadIdx.x;
    if (e >= E) return;
    int pos = atomicAdd(&cursor[dst[e]], 1);
    adj[pos] = make_float4(__int_as_float(src[e]), ea[e * 3 + 0], ea[e * 3 + 1], ea[e * 3 + 2]);
}

// ---------------- W -> bf16 MFMA B-frags (+ We transposes in slot y==6) ----------------
struct WfragArgs {
    const float* W[6];
    short* WF[6];
    int din[6];
    int KP[6];
    const float* We1;
    const float* We2;
    float* WeT1;
    float* WeT2;
};

__global__ void wfrag_all_k(WfragArgs a) {
    int which = blockIdx.y;
    int idx = blockIdx.x * 256 + threadIdx.x;
    if (which == 6) {
        if (idx < 384) {
            int r = idx / 3, c = idx - r * 3;
            a.WeT1[c * 128 + r] = a.We1[idx];
        } else if (idx < 768) {
            int j = idx - 384;
            int r = j / 3, c = j - r * 3;
            a.WeT2[c * 128 + r] = a.We2[j];
        }
        return;
    }
    int din = a.din[which], KP = a.KP[which];
    const float* W = a.W[which];
    short* WF = a.WF[which];
    int NC = KP >> 3;
    int total = 8 * NC * 16;
    if (idx >= total) return;
    int n16 = idx & 15;
    int rest = idx >> 4;
    int c = rest % NC;
    int nt = rest / NC;
    int n = nt * 16 + n16;
    union { short s[8]; int4 v; } u;
#pragma unroll
    for (int j = 0; j < 8; ++j) {
        int k = c * 8 + j;
        float val = (k < din) ? W[(size_t)n * din + k] : 0.f;
        u.s[j] = f2bf(val);
    }
    ((int4*)WF)[idx] = u.v;
}

// ---------------- aggregation layer 0: y_bf16[n][32] = pad(x + sum relu(x[src]+Lin(ea))) ----------------
__global__ __launch_bounds__(256) void agg_d9_k(
    const unsigned short* __restrict__ xbf /*[n][16] bf16*/, const int* __restrict__ rowstart,
    const float4* __restrict__ adj,
    const float* __restrict__ We /*[9][3]*/, const float* __restrict__ be,
    unsigned short* __restrict__ y /*[n][32] bf16*/, int n) {
    int i = blockIdx.x * 256 + threadIdx.x;
    if (i >= n) return;
    float w0[9], w1[9], w2[9], bb[9], acc[9];
#pragma unroll
    for (int j = 0; j < 9; ++j) {
        w0[j] = We[j * 3 + 0];
        w1[j] = We[j * 3 + 1];
        w2[j] = We[j * 3 + 2];
        bb[j] = be[j];
    }
    {
        const int4* xr4 = (const int4*)(xbf + (size_t)i * 16);
        int4 a = xr4[0];
        int w8 = ((const int*)xbf)[(size_t)i * 8 + 4];
        acc[0] = blo(a.x); acc[1] = bhi(a.x);
        acc[2] = blo(a.y); acc[3] = bhi(a.y);
        acc[4] = blo(a.z); acc[5] = bhi(a.z);
        acc[6] = blo(a.w); acc[7] = bhi(a.w);
        acc[8] = blo(w8);
    }
    int k1 = rowstart[i + 1];
    for (int k = rowstart[i]; k < k1; ++k) {
        float4 ed = adj[k];
        int s = __float_as_int(ed.x);
        float e0 = ed.y, e1 = ed.z, e2 = ed.w;
        int4 a = *(const int4*)(xbf + (size_t)s * 16);
        int w8 = ((const int*)xbf)[(size_t)s * 8 + 4];
        float xv[9] = {blo(a.x), bhi(a.x), blo(a.y), bhi(a.y),
                       blo(a.z), bhi(a.z), blo(a.w), bhi(a.w), blo(w8)};
#pragma unroll
        for (int j = 0; j < 9; ++j) {
            float lin = fmaf(w0[j], e0, fmaf(w1[j], e1, fmaf(w2[j], e2, bb[j])));
            acc[j] += fmaxf(xv[j] + lin, 0.f);
        }
    }
    union { unsigned short s[32]; int4 v[4]; } u;
#pragma unroll
    for (int j = 0; j < 9; ++j) u.s[j] = (unsigned short)f2bf(acc[j]);
#pragma unroll
    for (int j = 9; j < 32; ++j) u.s[j] = 0;
    int4* yp = (int4*)(y + (size_t)i * 32);
#pragma unroll
    for (int j = 0; j < 4; ++j) yp[j] = u.v[j];
}

// ---------------- aggregation d=128: one wave/node, edge-halves, 4-deep ILP; bf16 h in/out ----------------
__global__ __launch_bounds__(256) void agg_d128_k(
    const unsigned short* __restrict__ hbf, const int* __restrict__ rowstart,
    const float4* __restrict__ adj,
    const float* __restrict__ WeT /*[3][128]*/, const float* __restrict__ be,
    unsigned short* __restrict__ y /*[n][128] bf16*/, int n) {
    int lane = threadIdx.x & 63;
    int node = blockIdx.x * 4 + (threadIdx.x >> 6);
    if (node >= n) return;
    int l31 = lane & 31, half = lane >> 5;
    int c = l31 * 4;
    float4 w0 = ld4(&WeT[0 * 128 + c]);
    float4 w1 = ld4(&WeT[1 * 128 + c]);
    float4 w2 = ld4(&WeT[2 * 128 + c]);
    float4 b4 = ld4(&be[c]);
    float4 acc = make_float4(0.f, 0.f, 0.f, 0.f);
    const ushort4* hb = (const ushort4*)hbf;
    int k1 = rowstart[node + 1];
    int k = rowstart[node] + half;
    for (; k + 6 < k1; k += 8) {
        float4 e[4] = {adj[k], adj[k + 2], adj[k + 4], adj[k + 6]};
        ushort4 u[4];
#pragma unroll
        for (int j = 0; j < 4; ++j) u[j] = hb[(size_t)__float_as_int(e[j].x) * 32 + l31];
#pragma unroll
        for (int j = 0; j < 4; ++j) {
            float e0 = e[j].y, e1 = e[j].z, e2 = e[j].w;
            acc.x += fmaxf(fmaf(w0.x, e0, fmaf(w1.x, e1, fmaf(w2.x, e2, b4.x))) + bu2f(u[j].x), 0.f);
            acc.y += fmaxf(fmaf(w0.y, e0, fmaf(w1.y, e1, fmaf(w2.y, e2, b4.y))) + bu2f(u[j].y), 0.f);
            acc.z += fmaxf(fmaf(w0.z, e0, fmaf(w1.z, e1, fmaf(w2.z, e2, b4.z))) + bu2f(u[j].z), 0.f);
            acc.w += fmaxf(fmaf(w0.w, e0, fmaf(w1.w, e1, fmaf(w2.w, e2, b4.w))) + bu2f(u[j].w), 0.f);
        }
    }
    for (; k < k1; k += 2) {
        float4 ed = adj[k];
        int s = __float_as_int(ed.x);
        float e0 = ed.y, e1 = ed.z, e2 = ed.w;
        ushort4 ua = hb[(size_t)s * 32 + l31];
        acc.x += fmaxf(fmaf(w0.x, e0, fmaf(w1.x, e1, fmaf(w2.x, e2, b4.x))) + bu2f(ua.x), 0.f);
        acc.y += fmaxf(fmaf(w0.y, e0, fmaf(w1.y, e1, fmaf(w2.y, e2, b4.y))) + bu2f(ua.y), 0.f);
        acc.z += fmaxf(fmaf(w0.z, e0, fmaf(w1.z, e1, fmaf(w2.z, e2, b4.z))) + bu2f(ua.z), 0.f);
        acc.w += fmaxf(fmaf(w0.w, e0, fmaf(w1.w, e1, fmaf(w2.w, e2, b4.w))) + bu2f(ua.w), 0.f);
    }
    acc.x += __shfl_xor(acc.x, 32);
    acc.y += __shfl_xor(acc.y, 32);
    acc.z += __shfl_xor(acc.z, 32);
    acc.w += __shfl_xor(acc.w, 32);
    if (half == 0) {
        ushort4 xv = hb[(size_t)node * 32 + l31];
        ushort4 o;
        o.x = (unsigned short)f2bf(acc.x + bu2f(xv.x));
        o.y = (unsigned short)f2bf(acc.y + bu2f(xv.y));
        o.z = (unsigned short)f2bf(acc.z + bu2f(xv.z));
        o.w = (unsigned short)f2bf(acc.w + bu2f(xv.w));
        ((ushort4*)y)[(size_t)node * 32 + l31] = o;
    }
}

// ---------------- A-fragment helpers ----------------
__device__ __forceinline__ bf16x8 loadAbf(const unsigned short* p, bool v) {
    if (v) return *(const bf16x8*)p;
    bf16x8 z = {0, 0, 0, 0, 0, 0, 0, 0};
    return z;
}

__device__ __forceinline__ bf16x8 loadA_bn(const unsigned short* p, bool v,
                                           float4 sc0, float4 sc1, float4 sh0, float4 sh1) {
    union { short s[8]; bf16x8 v8; } u;
    if (v) {
        union { ushort4 q[2]; unsigned short s[8]; } iv;
        iv.q[0] = *(const ushort4*)p;
        iv.q[1] = *(const ushort4*)(p + 4);
        u.s[0] = f2bf(fmaxf(fmaf(bu2f(iv.s[0]), sc0.x, sh0.x), 0.f));
        u.s[1] = f2bf(fmaxf(fmaf(bu2f(iv.s[1]), sc0.y, sh0.y), 0.f));
        u.s[2] = f2bf(fmaxf(fmaf(bu2f(iv.s[2]), sc0.z, sh0.z), 0.f));
        u.s[3] = f2bf(fmaxf(fmaf(bu2f(iv.s[3]), sc0.w, sh0.w), 0.f));
        u.s[4] = f2bf(fmaxf(fmaf(bu2f(iv.s[4]), sc1.x, sh1.x), 0.f));
        u.s[5] = f2bf(fmaxf(fmaf(bu2f(iv.s[5]), sc1.y, sh1.y), 0.f));
        u.s[6] = f2bf(fmaxf(fmaf(bu2f(iv.s[6]), sc1.z, sh1.z), 0.f));
        u.s[7] = f2bf(fmaxf(fmaf(bu2f(iv.s[7]), sc1.w, sh1.w), 0.f));
    } else {
#pragma unroll
        for (int j = 0; j < 8; ++j) u.s[j] = 0;
    }
    return u.v8;
}

// ---------------- MFMA GEMM1: H(bf16) = Y(bf16) @ Wt, + BN column stats ----------------
template <int KP>
__global__ __launch_bounds__(256) void mgemm1_k(
    const unsigned short* Y /* [n][KP] bf16 */, const short* __restrict__ WF,
    unsigned short* Hout /* [n][128] bf16 */, float* __restrict__ col_sum,
    float* __restrict__ col_sumsq, int n) {
    constexpr int NC = KP / 8;
    constexpr int KB = KP / 32;
    __shared__ short Wlds[8 * NC * 16 * 8];
    __shared__ float red[256];
    const int t = threadIdx.x;
    const int lane = t & 63, w = t >> 6;
    const int l15 = lane & 15, q = lane >> 4;
    const int row0 = blockIdx.x * 128 + w * 32;

    {
        const int4* s = (const int4*)WF;
        int4* d = (int4*)Wlds;
        for (int i = t; i < 8 * NC * 16; i += 256) d[i] = s[i];
    }
    red[t] = 0.f;
    __syncthreads();

    f32x4 acc[2][8];
#pragma unroll
    for (int rt = 0; rt < 2; ++rt)
#pragma unroll
        for (int nt = 0; nt < 8; ++nt) acc[rt][nt] = (f32x4){0.f, 0.f, 0.f, 0.f};

    const int r0 = row0 + l15, r1 = row0 + 16 + l15;
    const unsigned short* p0 = Y + (size_t)r0 * KP + q * 8;
    const unsigned short* p1 = Y + (size_t)r1 * KP + q * 8;
    const bool v0 = r0 < n, v1 = r1 < n;
    const bf16x8* WL = (const bf16x8*)Wlds;

#pragma unroll
    for (int b = 0; b < KB; ++b) {
        bf16x8 a0 = loadAbf(p0 + b * 32, v0);
        bf16x8 a1 = loadAbf(p1 + b * 32, v1);
#pragma unroll
        for (int nt = 0; nt < 8; ++nt) {
            bf16x8 bf = WL[(nt * NC + b * 4 + q) * 16 + l15];
            acc[0][nt] = __builtin_amdgcn_mfma_f32_16x16x32_bf16(a0, bf, acc[0][nt], 0, 0, 0);
            acc[1][nt] = __builtin_amdgcn_mfma_f32_16x16x32_bf16(a1, bf, acc[1][nt], 0, 0, 0);
        }
    }

#pragma unroll
    for (int nt = 0; nt < 8; ++nt) {
        float s = 0.f, ss = 0.f;
#pragma unroll
        for (int rt = 0; rt < 2; ++rt) {
            int rb = row0 + rt * 16 + q * 4;
#pragma unroll
            for (int i = 0; i < 4; ++i) {
                float d = acc[rt][nt][i];
                int r = rb + i;
                if (r < n) Hout[(size_t)r * 128 + nt * 16 + l15] = (unsigned short)f2bf(d);
                s += d;
                ss += d * d;
            }
        }
        s += __shfl_xor(s, 16);
        s += __shfl_xor(s, 32);
        ss += __shfl_xor(ss, 16);
        ss += __shfl_xor(ss, 32);
        if (lane < 16) {
            atomicAdd(&red[nt * 16 + l15], s);
            atomicAdd(&red[128 + nt * 16 + l15], ss);
        }
    }
    __syncthreads();
    if (t < 128) atomicAdd(&col_sum[t], red[t]);
    else atomicAdd(&col_sumsq[t - 128], red[t]);
}

// ---------------- MFMA GEMM2 (fused BN finalize + bias/relu + graph pool); bf16 in/out ----------------
__global__ __launch_bounds__(256) void mgemm2_k(
    const unsigned short* Hpre /* bf16 */, const short* __restrict__ WF,
    const float* __restrict__ col_sum, const float* __restrict__ col_sumsq,
    const float* __restrict__ gw, const float* __restrict__ bw,
    const float* __restrict__ bias,
    const int* __restrict__ batch, const int* __restrict__ gstart,
    unsigned short* __restrict__ Hbf /* bf16 out, may be null */,
    float* __restrict__ outp, int n) {
    constexpr int NC = 16;
    __shared__ __align__(16) char smem[64 * 132 * 4];  // union: Wlds (32 KB) / Llds (33 KB)
    __shared__ float scsh[256];
    short* Wlds = (short*)smem;
    float* Llds = (float*)smem;
    const int t = threadIdx.x;
    const int lane = t & 63, w = t >> 6;
    const int l15 = lane & 15, q = lane >> 4;
    const int row0 = blockIdx.x * 128 + w * 32;

    {
        const int4* s = (const int4*)WF;
        int4* d = (int4*)Wlds;
        for (int i = t; i < 8 * NC * 16; i += 256) d[i] = s[i];
    }
    if (t < 128) {
        float inv_n = 1.0f / (float)n;
        float mean = col_sum[t] * inv_n;
        float var = col_sumsq[t] * inv_n - mean * mean;
        float a = gw[t] * rsqrtf(var + BN_EPS);
        scsh[t] = a;
        scsh[128 + t] = fmaf(-mean, a, bw[t]);
    }
    __syncthreads();

    f32x4 acc[2][8];
#pragma unroll
    for (int rt = 0; rt < 2; ++rt)
#pragma unroll
        for (int nt = 0; nt < 8; ++nt) acc[rt][nt] = (f32x4){0.f, 0.f, 0.f, 0.f};

    const int r0 = row0 + l15, r1 = row0 + 16 + l15;
    const unsigned short* p0 = Hpre + (size_t)r0 * 128 + q * 8;
    const unsigned short* p1 = Hpre + (size_t)r1 * 128 + q * 8;
    const bool v0 = r0 < n, v1 = r1 < n;
    const bf16x8* WL = (const bf16x8*)Wlds;

#pragma unroll
    for (int b = 0; b < 4; ++b) {
        const int k0 = b * 32 + q * 8;
        float4 sc0 = ld4(&scsh[k0]), sc1 = ld4(&scsh[k0 + 4]);
        float4 sh0 = ld4(&scsh[128 + k0]), sh1 = ld4(&scsh[128 + k0 + 4]);
        bf16x8 a0 = loadA_bn(p0 + b * 32, v0, sc0, sc1, sh0, sh1);
        bf16x8 a1 = loadA_bn(p1 + b * 32, v1, sc0, sc1, sh0, sh1);
#pragma unroll
        for (int nt = 0; nt < 8; ++nt) {
            bf16x8 bf = WL[(nt * NC + b * 4 + q) * 16 + l15];
            acc[0][nt] = __builtin_amdgcn_mfma_f32_16x16x32_bf16(a0, bf, acc[0][nt], 0, 0, 0);
            acc[1][nt] = __builtin_amdgcn_mfma_f32_16x16x32_bf16(a1, bf, acc[1][nt], 0, 0, 0);
        }
    }

    __syncthreads();  // all waves done with Wlds before overwrite

#pragma unroll
    for (int hb = 0; hb < 2; ++hb) {
        const int r0w = blockIdx.x * 128 + hb * 64;
        if ((w >> 1) == hb) {
#pragma unroll
            for (int nt = 0; nt < 8; ++nt) {
                float bcol = bias[nt * 16 + l15];
#pragma unroll
                for (int rt = 0; rt < 2; ++rt) {
                    int rb = row0 + rt * 16 + q * 4;
#pragma unroll
                    for (int i = 0; i < 4; ++i) {
                        int r = rb + i;
                        float o = 0.f;
                        if (r < n) {
                            o = fmaxf(acc[rt][nt][i] + bcol, 0.f);
                            if (Hbf) Hbf[(size_t)r * 128 + nt * 16 + l15] = (unsigned short)f2bf(o);
                        }
                        Llds[(r - r0w) * 132 + nt * 16 + l15] = o;
                    }
                }
            }
        }
        __syncthreads();
        if (r0w < n) {
            int c = t & 127, half = t >> 7;
            int g = batch[r0w];
            while (g < N_GRAPHS) {
                int segs = max(gstart[g], r0w);
                int sege = min(gstart[g + 1], r0w + 64);
                if (segs >= r0w + 64) break;
                float s = 0.f;
                for (int r = segs + half; r < sege; r += 2) s += Llds[(r - r0w) * 132 + c];
                if (s != 0.f) atomicAdd(&outp[(size_t)g * OUT_STRIDE + c], s);
                if (gstart[g + 1] >= r0w + 64) break;
                ++g;
            }
        }
        __syncthreads();
    }
}

extern "C" void kernel_launch(void* const* d_in, const int* in_sizes, int n_in,
                              void* d_out, int out_size, void* d_ws, size_t ws_size,
                              hipStream_t stream) {
    const float* x = (const float*)d_in[0];
    const int* ei = (const int*)d_in[1];
    const float* ea = (const float*)d_in[2];
    const int* batch = (const int*)d_in[3];
    const int* srcArr = ei;
    const int* dstArr = ei + N_EDGES;

    const float *We[3], *be[3], *W1[3], *gP[3], *bP[3], *W2[3], *b2[3];
    for (int l = 0; l < 3; ++l) {
        int base = 4 + 7 * l;
        We[l] = (const float*)d_in[base + 0];
        be[l] = (const float*)d_in[base + 1];
        W1[l] = (const float*)d_in[base + 2];
        gP[l] = (const float*)d_in[base + 3];
        bP[l] = (const float*)d_in[base + 4];
        W2[l] = (const float*)d_in[base + 5];
        b2[l] = (const float*)d_in[base + 6];
    }

    char* w = (char*)d_ws;
    auto carve = [&](size_t bytes) {
        char* p = w;
        w += (bytes + 255) & ~(size_t)255;
        return p;
    };
    int* deg = (int*)carve((size_t)N_NODES * 4);
    int* rowstart = (int*)carve((size_t)(N_NODES + 1) * 4);
    int* cursor = (int*)carve((size_t)N_NODES * 4);
    int* bsum = (int*)carve((size_t)SCAN_NB * 4);
    int* boff = (int*)carve((size_t)SCAN_NB * 4);
    int* gstart = (int*)carve((size_t)(N_GRAPHS + 1) * 4);
    float4* adj = (float4*)carve((size_t)N_EDGES * 16);
    float* WeT1 = (float*)carve(3 * 128 * 4);
    float* WeT2 = (float*)carve(3 * 128 * 4);
    short* WF1_0 = (short*)carve(8 * 4 * 16 * 8 * 2);    // KP=32
    short* WF1_1 = (short*)carve(8 * 16 * 16 * 8 * 2);   // KP=128
    short* WF1_2 = (short*)carve(8 * 16 * 16 * 8 * 2);
    short* WF2_0 = (short*)carve(8 * 16 * 16 * 8 * 2);
    short* WF2_1 = (short*)carve(8 * 16 * 16 * 8 * 2);
    short* WF2_2 = (short*)carve(8 * 16 * 16 * 8 * 2);
    float* stats = (float*)carve(3 * 256 * 4);           // per-layer col_sum/col_sumsq
    unsigned short* xbf = (unsigned short*)carve((size_t)N_NODES * 16 * 2);
    unsigned short* y0p = (unsigned short*)carve((size_t)N_NODES * 32 * 2);
    unsigned short* hbufA = (unsigned short*)carve((size_t)N_NODES * 128 * 2);
    unsigned short* hbufB = (unsigned short*)carve((size_t)N_NODES * 128 * 2);

    hipMemsetAsync(deg, 0, (size_t)N_NODES * 4, stream);
    hipMemsetAsync(stats, 0, 3 * 256 * 4, stream);
    hipMemsetAsync(d_out, 0, (size_t)out_size * 4, stream);

    prep_k<<<(N_EDGES + 255) / 256, 256, 0, stream>>>(dstArr, deg, x, xbf, batch, gstart,
                                                      N_EDGES, N_NODES, N_GRAPHS);
    deg_bsum_k<<<SCAN_NB, 256, 0, stream>>>(deg, bsum, N_NODES);
    bsum_scan_k<<<1, 256, 0, stream>>>(bsum, boff, rowstart, SCAN_NB, N_NODES);
    deg_scan_k<<<SCAN_NB, 256, 0, stream>>>(deg, boff, rowstart, cursor, N_NODES);
    csr_fill_k<<<(N_EDGES + 255) / 256, 256, 0, stream>>>(srcArr, dstArr, ea, cursor, adj, N_EDGES);

    {
        WfragArgs wa;
        wa.W[0] = W1[0]; wa.WF[0] = WF1_0; wa.din[0] = 9;   wa.KP[0] = 32;
        wa.W[1] = W1[1]; wa.WF[1] = WF1_1; wa.din[1] = 128; wa.KP[1] = 128;
        wa.W[2] = W1[2]; wa.WF[2] = WF1_2; wa.din[2] = 128; wa.KP[2] = 128;
        wa.W[3] = W2[0]; wa.WF[3] = WF2_0; wa.din[3] = 128; wa.KP[3] = 128;
        wa.W[4] = W2[1]; wa.WF[4] = WF2_1; wa.din[4] = 128; wa.KP[4] = 128;
        wa.W[5] = W2[2]; wa.WF[5] = WF2_2; wa.din[5] = 128; wa.KP[5] = 128;
        wa.We1 = We[1]; wa.We2 = We[2]; wa.WeT1 = WeT1; wa.WeT2 = WeT2;
        dim3 gw(8, 7);
        wfrag_all_k<<<gw, 256, 0, stream>>>(wa);
    }

    const int gM = (N_NODES + 127) / 128;
    const int gAgg = (N_NODES + 3) / 4;
    float* out_f = (float*)d_out;

    // ---- layer 0 (K=32 padded from din=9) ----
    agg_d9_k<<<(N_NODES + 255) / 256, 256, 0, stream>>>(xbf, rowstart, adj, We[0], be[0], y0p, N_NODES);
    mgemm1_k<32><<<gM, 256, 0, stream>>>(y0p, WF1_0, hbufB, stats, stats + 128, N_NODES);
    mgemm2_k<<<gM, 256, 0, stream>>>(hbufB, WF2_0, stats, stats + 128, gP[0], bP[0], b2[0],
                                     batch, gstart, hbufA, out_f + 0, N_NODES);

    // ---- layer 1 ----
    agg_d128_k<<<gAgg, 256, 0, stream>>>(hbufA, rowstart, adj, WeT1, be[1], hbufB, N_NODES);
    mgemm1_k<128><<<gM, 256, 0, stream>>>(hbufB, WF1_1, hbufB, stats + 256, stats + 384, N_NODES);
    mgemm2_k<<<gM, 256, 0, stream>>>(hbufB, WF2_1, stats + 256, stats + 384, gP[1], bP[1], b2[1],
                                     batch, gstart, hbufA, out_f + 128, N_NODES);

    // ---- layer 2 ----
    agg_d128_k<<<gAgg, 256, 0, stream>>>(hbufA, rowstart, adj, WeT2, be[2], hbufB, N_NODES);
    mgemm1_k<128><<<gM, 256, 0, stream>>>(hbufB, WF1_2, hbufB, stats + 512, stats + 640, N_NODES);
    mgemm2_k<<<gM, 256, 0, stream>>>(hbufB, WF2_2, stats + 512, stats + 640, gP[2], bP[2], b2[2],
                                     batch, gstart, nullptr, out_f + 256, N_NODES);
}

// Round 12
// 416.613 us; speedup vs baseline: 1.0754x; 1.0754x over previous
//
#include <hip/hip_runtime.h>

#define N_NODES 50000
#define N_EDGES 800000
#define N_GRAPHS 500
#define DH 128
#define OUT_STRIDE 384
#define BN_EPS 1e-5f
#define SCAN_NB ((N_NODES + 255) / 256)

typedef __attribute__((ext_vector_type(8))) short bf16x8;
typedef __attribute__((ext_vector_type(4))) float f32x4;

__device__ __forceinline__ float4 ld4(const float* p) { return *(const float4*)p; }
__device__ __forceinline__ void st4(float* p, float4 v) { *(float4*)p = v; }

__device__ __forceinline__ short f2bf(float f) {
    union { float f; unsigned u; } v; v.f = f;
    unsigned r = v.u + 0x7FFFu + ((v.u >> 16) & 1u);
    return (short)(r >> 16);
}
__device__ __forceinline__ float bu2f(unsigned short v) {
    union { unsigned u; float f; } x; x.u = ((unsigned)v) << 16; return x.f;
}
__device__ __forceinline__ float blo(int w) {
    union { unsigned u; float f; } x; x.u = ((unsigned)w) << 16; return x.f;
}
__device__ __forceinline__ float bhi(int w) {
    union { unsigned u; float f; } x; x.u = (unsigned)w & 0xFFFF0000u; return x.f;
}

// ---------------- fused prep: deg count + edge rank (edge) + x->bf16[16] + graph bounds (node) ----------------
__global__ void prep_k(const int* __restrict__ dst, int* __restrict__ deg,
                       int* __restrict__ rankArr,
                       const float* __restrict__ x, unsigned short* __restrict__ xbf,
                       const int* __restrict__ batch, int* __restrict__ gstart,
                       int E, int n, int G) {
    int i = blockIdx.x * 256 + threadIdx.x;
    if (i < E) rankArr[i] = atomicAdd(&deg[dst[i]], 1);
    if (i < n) {
        const float* s = x + (size_t)i * 9;
        union { unsigned short u[16]; int4 v[2]; } o;
#pragma unroll
        for (int j = 0; j < 9; ++j) o.u[j] = (unsigned short)f2bf(s[j]);
#pragma unroll
        for (int j = 9; j < 16; ++j) o.u[j] = 0;
        int4* d = (int4*)(xbf + (size_t)i * 16);
        d[0] = o.v[0];
        d[1] = o.v[1];
        int b = batch[i];
        if (i == 0) {
            for (int g = 0; g <= b; ++g) gstart[g] = 0;
        } else {
            int p = batch[i - 1];
            for (int g = p + 1; g <= b; ++g) gstart[g] = i;
        }
        if (i == n - 1) {
            for (int g = b + 1; g <= G; ++g) gstart[g] = n;
        }
    }
}

// hierarchical scan
__global__ void deg_bsum_k(const int* __restrict__ deg, int* __restrict__ bsum, int n) {
    __shared__ int red[256];
    int t = threadIdx.x, i = blockIdx.x * 256 + t;
    red[t] = (i < n) ? deg[i] : 0;
    __syncthreads();
    for (int off = 128; off > 0; off >>= 1) {
        if (t < off) red[t] += red[t + off];
        __syncthreads();
    }
    if (t == 0) bsum[blockIdx.x] = red[0];
}

__global__ void bsum_scan_k(const int* __restrict__ bsum, int* __restrict__ boff,
                            int* __restrict__ rowstart, int nb, int n) {
    __shared__ int s[256];
    int t = threadIdx.x;
    int v = (t < nb) ? bsum[t] : 0;
    s[t] = v;
    __syncthreads();
    for (int off = 1; off < 256; off <<= 1) {
        int u = (t >= off) ? s[t - off] : 0;
        __syncthreads();
        s[t] += u;
        __syncthreads();
    }
    if (t < nb) boff[t] = s[t] - v;
    if (t == 255) rowstart[n] = s[255];
}

__global__ void deg_scan_k(const int* __restrict__ deg, const int* __restrict__ boff,
                           int* __restrict__ rowstart, int n) {
    __shared__ int s[256];
    int t = threadIdx.x, i = blockIdx.x * 256 + t;
    int v = (i < n) ? deg[i] : 0;
    s[t] = v;
    __syncthreads();
    for (int off = 1; off < 256; off <<= 1) {
        int u = (t >= off) ? s[t - off] : 0;
        __syncthreads();
        s[t] += u;
        __syncthreads();
    }
    if (i < n) rowstart[i] = boff[blockIdx.x] + s[t] - v;
}

// atomic-free CSR fill: pos = rowstart[dst] + precomputed rank. 16B record {src, e0,e1,e2}.
__global__ void csr_fill_k(const int* __restrict__ src, const int* __restrict__ dst,
                           const int* __restrict__ rankArr, const int* __restrict__ rowstart,
                           const float* __restrict__ ea, float4* __restrict__ adj, int E) {
    int e = blockIdx.x * 256 + threadIdx.x;
    if (e >= E) return;
    int pos = rowstart[dst[e]] + rankArr[e];
    adj[pos] = make_float4(__int_as_float(src[e]), ea[e * 3 + 0], ea[e * 3 + 1], ea[e * 3 + 2]);
}

// ---------------- W -> bf16 MFMA B-frags (+ We transposes in slot y==6) ----------------
struct WfragArgs {
    const float* W[6];
    short* WF[6];
    int din[6];
    int KP[6];
    const float* We1;
    const float* We2;
    float* WeT1;
    float* WeT2;
};

__global__ void wfrag_all_k(WfragArgs a) {
    int which = blockIdx.y;
    int idx = blockIdx.x * 256 + threadIdx.x;
    if (which == 6) {
        if (idx < 384) {
            int r = idx / 3, c = idx - r * 3;
            a.WeT1[c * 128 + r] = a.We1[idx];
        } else if (idx < 768) {
            int j = idx - 384;
            int r = j / 3, c = j - r * 3;
            a.WeT2[c * 128 + r] = a.We2[j];
        }
        return;
    }
    int din = a.din[which], KP = a.KP[which];
    const float* W = a.W[which];
    short* WF = a.WF[which];
    int NC = KP >> 3;
    int total = 8 * NC * 16;
    if (idx >= total) return;
    int n16 = idx & 15;
    int rest = idx >> 4;
    int c = rest % NC;
    int nt = rest / NC;
    int n = nt * 16 + n16;
    union { short s[8]; int4 v; } u;
#pragma unroll
    for (int j = 0; j < 8; ++j) {
        int k = c * 8 + j;
        float val = (k < din) ? W[(size_t)n * din + k] : 0.f;
        u.s[j] = f2bf(val);
    }
    ((int4*)WF)[idx] = u.v;
}

// ---------------- aggregation layer 0: y_bf16[n][32] = pad(x + sum relu(x[src]+Lin(ea))) ----------------
__global__ __launch_bounds__(256) void agg_d9_k(
    const unsigned short* __restrict__ xbf /*[n][16] bf16*/, const int* __restrict__ rowstart,
    const float4* __restrict__ adj,
    const float* __restrict__ We /*[9][3]*/, const float* __restrict__ be,
    unsigned short* __restrict__ y /*[n][32] bf16*/, int n) {
    int i = blockIdx.x * 256 + threadIdx.x;
    if (i >= n) return;
    float w0[9], w1[9], w2[9], bb[9], acc[9];
#pragma unroll
    for (int j = 0; j < 9; ++j) {
        w0[j] = We[j * 3 + 0];
        w1[j] = We[j * 3 + 1];
        w2[j] = We[j * 3 + 2];
        bb[j] = be[j];
    }
    {
        const int4* xr4 = (const int4*)(xbf + (size_t)i * 16);
        int4 a = xr4[0];
        int w8 = ((const int*)xbf)[(size_t)i * 8 + 4];
        acc[0] = blo(a.x); acc[1] = bhi(a.x);
        acc[2] = blo(a.y); acc[3] = bhi(a.y);
        acc[4] = blo(a.z); acc[5] = bhi(a.z);
        acc[6] = blo(a.w); acc[7] = bhi(a.w);
        acc[8] = blo(w8);
    }
    int k1 = rowstart[i + 1];
    for (int k = rowstart[i]; k < k1; ++k) {
        float4 ed = adj[k];
        int s = __float_as_int(ed.x);
        float e0 = ed.y, e1 = ed.z, e2 = ed.w;
        int4 a = *(const int4*)(xbf + (size_t)s * 16);
        int w8 = ((const int*)xbf)[(size_t)s * 8 + 4];
        float xv[9] = {blo(a.x), bhi(a.x), blo(a.y), bhi(a.y),
                       blo(a.z), bhi(a.z), blo(a.w), bhi(a.w), blo(w8)};
#pragma unroll
        for (int j = 0; j < 9; ++j) {
            float lin = fmaf(w0[j], e0, fmaf(w1[j], e1, fmaf(w2[j], e2, bb[j])));
            acc[j] += fmaxf(xv[j] + lin, 0.f);
        }
    }
    union { unsigned short s[32]; int4 v[4]; } u;
#pragma unroll
    for (int j = 0; j < 9; ++j) u.s[j] = (unsigned short)f2bf(acc[j]);
#pragma unroll
    for (int j = 9; j < 32; ++j) u.s[j] = 0;
    int4* yp = (int4*)(y + (size_t)i * 32);
#pragma unroll
    for (int j = 0; j < 4; ++j) yp[j] = u.v[j];
}

// ---------------- aggregation d=128: one wave/node, edge-halves, 4-deep ILP; bf16 h in/out ----------------
__global__ __launch_bounds__(256) void agg_d128_k(
    const unsigned short* __restrict__ hbf, const int* __restrict__ rowstart,
    const float4* __restrict__ adj,
    const float* __restrict__ WeT /*[3][128]*/, const float* __restrict__ be,
    unsigned short* __restrict__ y /*[n][128] bf16*/, int n) {
    int lane = threadIdx.x & 63;
    int node = blockIdx.x * 4 + (threadIdx.x >> 6);
    if (node >= n) return;
    int l31 = lane & 31, half = lane >> 5;
    int c = l31 * 4;
    float4 w0 = ld4(&WeT[0 * 128 + c]);
    float4 w1 = ld4(&WeT[1 * 128 + c]);
    float4 w2 = ld4(&WeT[2 * 128 + c]);
    float4 b4 = ld4(&be[c]);
    float4 acc = make_float4(0.f, 0.f, 0.f, 0.f);
    const ushort4* hb = (const ushort4*)hbf;
    int k1 = rowstart[node + 1];
    int k = rowstart[node] + half;
    for (; k + 6 < k1; k += 8) {
        float4 e[4] = {adj[k], adj[k + 2], adj[k + 4], adj[k + 6]};
        ushort4 u[4];
#pragma unroll
        for (int j = 0; j < 4; ++j) u[j] = hb[(size_t)__float_as_int(e[j].x) * 32 + l31];
#pragma unroll
        for (int j = 0; j < 4; ++j) {
            float e0 = e[j].y, e1 = e[j].z, e2 = e[j].w;
            acc.x += fmaxf(fmaf(w0.x, e0, fmaf(w1.x, e1, fmaf(w2.x, e2, b4.x))) + bu2f(u[j].x), 0.f);
            acc.y += fmaxf(fmaf(w0.y, e0, fmaf(w1.y, e1, fmaf(w2.y, e2, b4.y))) + bu2f(u[j].y), 0.f);
            acc.z += fmaxf(fmaf(w0.z, e0, fmaf(w1.z, e1, fmaf(w2.z, e2, b4.z))) + bu2f(u[j].z), 0.f);
            acc.w += fmaxf(fmaf(w0.w, e0, fmaf(w1.w, e1, fmaf(w2.w, e2, b4.w))) + bu2f(u[j].w), 0.f);
        }
    }
    for (; k < k1; k += 2) {
        float4 ed = adj[k];
        int s = __float_as_int(ed.x);
        float e0 = ed.y, e1 = ed.z, e2 = ed.w;
        ushort4 ua = hb[(size_t)s * 32 + l31];
        acc.x += fmaxf(fmaf(w0.x, e0, fmaf(w1.x, e1, fmaf(w2.x, e2, b4.x))) + bu2f(ua.x), 0.f);
        acc.y += fmaxf(fmaf(w0.y, e0, fmaf(w1.y, e1, fmaf(w2.y, e2, b4.y))) + bu2f(ua.y), 0.f);
        acc.z += fmaxf(fmaf(w0.z, e0, fmaf(w1.z, e1, fmaf(w2.z, e2, b4.z))) + bu2f(ua.z), 0.f);
        acc.w += fmaxf(fmaf(w0.w, e0, fmaf(w1.w, e1, fmaf(w2.w, e2, b4.w))) + bu2f(ua.w), 0.f);
    }
    acc.x += __shfl_xor(acc.x, 32);
    acc.y += __shfl_xor(acc.y, 32);
    acc.z += __shfl_xor(acc.z, 32);
    acc.w += __shfl_xor(acc.w, 32);
    if (half == 0) {
        ushort4 xv = hb[(size_t)node * 32 + l31];
        ushort4 o;
        o.x = (unsigned short)f2bf(acc.x + bu2f(xv.x));
        o.y = (unsigned short)f2bf(acc.y + bu2f(xv.y));
        o.z = (unsigned short)f2bf(acc.z + bu2f(xv.z));
        o.w = (unsigned short)f2bf(acc.w + bu2f(xv.w));
        ((ushort4*)y)[(size_t)node * 32 + l31] = o;
    }
}

// ---------------- A-fragment helpers ----------------
__device__ __forceinline__ bf16x8 loadAbf(const unsigned short* p, bool v) {
    if (v) return *(const bf16x8*)p;
    bf16x8 z = {0, 0, 0, 0, 0, 0, 0, 0};
    return z;
}

__device__ __forceinline__ bf16x8 loadA_bn(const unsigned short* p, bool v,
                                           float4 sc0, float4 sc1, float4 sh0, float4 sh1) {
    union { short s[8]; bf16x8 v8; } u;
    if (v) {
        union { ushort4 q[2]; unsigned short s[8]; } iv;
        iv.q[0] = *(const ushort4*)p;
        iv.q[1] = *(const ushort4*)(p + 4);
        u.s[0] = f2bf(fmaxf(fmaf(bu2f(iv.s[0]), sc0.x, sh0.x), 0.f));
        u.s[1] = f2bf(fmaxf(fmaf(bu2f(iv.s[1]), sc0.y, sh0.y), 0.f));
        u.s[2] = f2bf(fmaxf(fmaf(bu2f(iv.s[2]), sc0.z, sh0.z), 0.f));
        u.s[3] = f2bf(fmaxf(fmaf(bu2f(iv.s[3]), sc0.w, sh0.w), 0.f));
        u.s[4] = f2bf(fmaxf(fmaf(bu2f(iv.s[4]), sc1.x, sh1.x), 0.f));
        u.s[5] = f2bf(fmaxf(fmaf(bu2f(iv.s[5]), sc1.y, sh1.y), 0.f));
        u.s[6] = f2bf(fmaxf(fmaf(bu2f(iv.s[6]), sc1.z, sh1.z), 0.f));
        u.s[7] = f2bf(fmaxf(fmaf(bu2f(iv.s[7]), sc1.w, sh1.w), 0.f));
    } else {
#pragma unroll
        for (int j = 0; j < 8; ++j) u.s[j] = 0;
    }
    return u.v8;
}

// ---------------- MFMA GEMM1: H(bf16) = Y(bf16) @ Wt, + BN column stats ----------------
template <int KP>
__global__ __launch_bounds__(256) void mgemm1_k(
    const unsigned short* Y /* [n][KP] bf16 */, const short* __restrict__ WF,
    unsigned short* Hout /* [n][128] bf16 */, float* __restrict__ col_sum,
    float* __restrict__ col_sumsq, int n) {
    constexpr int NC = KP / 8;
    constexpr int KB = KP / 32;
    __shared__ short Wlds[8 * NC * 16 * 8];
    __shared__ float red[256];
    const int t = threadIdx.x;
    const int lane = t & 63, w = t >> 6;
    const int l15 = lane & 15, q = lane >> 4;
    const int row0 = blockIdx.x * 128 + w * 32;

    {
        const int4* s = (const int4*)WF;
        int4* d = (int4*)Wlds;
        for (int i = t; i < 8 * NC * 16; i += 256) d[i] = s[i];
    }
    red[t] = 0.f;
    __syncthreads();

    f32x4 acc[2][8];
#pragma unroll
    for (int rt = 0; rt < 2; ++rt)
#pragma unroll
        for (int nt = 0; nt < 8; ++nt) acc[rt][nt] = (f32x4){0.f, 0.f, 0.f, 0.f};

    const int r0 = row0 + l15, r1 = row0 + 16 + l15;
    const unsigned short* p0 = Y + (size_t)r0 * KP + q * 8;
    const unsigned short* p1 = Y + (size_t)r1 * KP + q * 8;
    const bool v0 = r0 < n, v1 = r1 < n;
    const bf16x8* WL = (const bf16x8*)Wlds;

#pragma unroll
    for (int b = 0; b < KB; ++b) {
        bf16x8 a0 = loadAbf(p0 + b * 32, v0);
        bf16x8 a1 = loadAbf(p1 + b * 32, v1);
#pragma unroll
        for (int nt = 0; nt < 8; ++nt) {
            bf16x8 bf = WL[(nt * NC + b * 4 + q) * 16 + l15];
            acc[0][nt] = __builtin_amdgcn_mfma_f32_16x16x32_bf16(a0, bf, acc[0][nt], 0, 0, 0);
            acc[1][nt] = __builtin_amdgcn_mfma_f32_16x16x32_bf16(a1, bf, acc[1][nt], 0, 0, 0);
        }
    }

#pragma unroll
    for (int nt = 0; nt < 8; ++nt) {
        float s = 0.f, ss = 0.f;
#pragma unroll
        for (int rt = 0; rt < 2; ++rt) {
            int rb = row0 + rt * 16 + q * 4;
#pragma unroll
            for (int i = 0; i < 4; ++i) {
                float d = acc[rt][nt][i];
                int r = rb + i;
                if (r < n) Hout[(size_t)r * 128 + nt * 16 + l15] = (unsigned short)f2bf(d);
                s += d;
                ss += d * d;
            }
        }
        s += __shfl_xor(s, 16);
        s += __shfl_xor(s, 32);
        ss += __shfl_xor(ss, 16);
        ss += __shfl_xor(ss, 32);
        if (lane < 16) {
            atomicAdd(&red[nt * 16 + l15], s);
            atomicAdd(&red[128 + nt * 16 + l15], ss);
        }
    }
    __syncthreads();
    if (t < 128) atomicAdd(&col_sum[t], red[t]);
    else atomicAdd(&col_sumsq[t - 128], red[t]);
}

// ---------------- MFMA GEMM2 (fused BN finalize + bias/relu + graph pool); bf16 in/out ----------------
__global__ __launch_bounds__(256) void mgemm2_k(
    const unsigned short* Hpre /* bf16 */, const short* __restrict__ WF,
    const float* __restrict__ col_sum, const float* __restrict__ col_sumsq,
    const float* __restrict__ gw, const float* __restrict__ bw,
    const float* __restrict__ bias,
    const int* __restrict__ batch, const int* __restrict__ gstart,
    unsigned short* __restrict__ Hbf /* bf16 out, may be null */,
    float* __restrict__ outp, int n) {
    constexpr int NC = 16;
    __shared__ __align__(16) char smem[64 * 132 * 4];  // union: Wlds (32 KB) / Llds (33 KB)
    __shared__ float scsh[256];
    short* Wlds = (short*)smem;
    float* Llds = (float*)smem;
    const int t = threadIdx.x;
    const int lane = t & 63, w = t >> 6;
    const int l15 = lane & 15, q = lane >> 4;
    const int row0 = blockIdx.x * 128 + w * 32;

    {
        const int4* s = (const int4*)WF;
        int4* d = (int4*)Wlds;
        for (int i = t; i < 8 * NC * 16; i += 256) d[i] = s[i];
    }
    if (t < 128) {
        float inv_n = 1.0f / (float)n;
        float mean = col_sum[t] * inv_n;
        float var = col_sumsq[t] * inv_n - mean * mean;
        float a = gw[t] * rsqrtf(var + BN_EPS);
        scsh[t] = a;
        scsh[128 + t] = fmaf(-mean, a, bw[t]);
    }
    __syncthreads();

    f32x4 acc[2][8];
#pragma unroll
    for (int rt = 0; rt < 2; ++rt)
#pragma unroll
        for (int nt = 0; nt < 8; ++nt) acc[rt][nt] = (f32x4){0.f, 0.f, 0.f, 0.f};

    const int r0 = row0 + l15, r1 = row0 + 16 + l15;
    const unsigned short* p0 = Hpre + (size_t)r0 * 128 + q * 8;
    const unsigned short* p1 = Hpre + (size_t)r1 * 128 + q * 8;
    const bool v0 = r0 < n, v1 = r1 < n;
    const bf16x8* WL = (const bf16x8*)Wlds;

#pragma unroll
    for (int b = 0; b < 4; ++b) {
        const int k0 = b * 32 + q * 8;
        float4 sc0 = ld4(&scsh[k0]), sc1 = ld4(&scsh[k0 + 4]);
        float4 sh0 = ld4(&scsh[128 + k0]), sh1 = ld4(&scsh[128 + k0 + 4]);
        bf16x8 a0 = loadA_bn(p0 + b * 32, v0, sc0, sc1, sh0, sh1);
        bf16x8 a1 = loadA_bn(p1 + b * 32, v1, sc0, sc1, sh0, sh1);
#pragma unroll
        for (int nt = 0; nt < 8; ++nt) {
            bf16x8 bf = WL[(nt * NC + b * 4 + q) * 16 + l15];
            acc[0][nt] = __builtin_amdgcn_mfma_f32_16x16x32_bf16(a0, bf, acc[0][nt], 0, 0, 0);
            acc[1][nt] = __builtin_amdgcn_mfma_f32_16x16x32_bf16(a1, bf, acc[1][nt], 0, 0, 0);
        }
    }

    __syncthreads();  // all waves done with Wlds before overwrite

#pragma unroll
    for (int hb = 0; hb < 2; ++hb) {
        const int r0w = blockIdx.x * 128 + hb * 64;
        if ((w >> 1) == hb) {
#pragma unroll
            for (int nt = 0; nt < 8; ++nt) {
                float bcol = bias[nt * 16 + l15];
#pragma unroll
                for (int rt = 0; rt < 2; ++rt) {
                    int rb = row0 + rt * 16 + q * 4;
#pragma unroll
                    for (int i = 0; i < 4; ++i) {
                        int r = rb + i;
                        float o = 0.f;
                        if (r < n) {
                            o = fmaxf(acc[rt][nt][i] + bcol, 0.f);
                            if (Hbf) Hbf[(size_t)r * 128 + nt * 16 + l15] = (unsigned short)f2bf(o);
                        }
                        Llds[(r - r0w) * 132 + nt * 16 + l15] = o;
                    }
                }
            }
        }
        __syncthreads();
        if (r0w < n) {
            int c = t & 127, half = t >> 7;
            int g = batch[r0w];
            while (g < N_GRAPHS) {
                int segs = max(gstart[g], r0w);
                int sege = min(gstart[g + 1], r0w + 64);
                if (segs >= r0w + 64) break;
                float s = 0.f;
                for (int r = segs + half; r < sege; r += 2) s += Llds[(r - r0w) * 132 + c];
                if (s != 0.f) atomicAdd(&outp[(size_t)g * OUT_STRIDE + c], s);
                if (gstart[g + 1] >= r0w + 64) break;
                ++g;
            }
        }
        __syncthreads();
    }
}

extern "C" void kernel_launch(void* const* d_in, const int* in_sizes, int n_in,
                              void* d_out, int out_size, void* d_ws, size_t ws_size,
                              hipStream_t stream) {
    const float* x = (const float*)d_in[0];
    const int* ei = (const int*)d_in[1];
    const float* ea = (const float*)d_in[2];
    const int* batch = (const int*)d_in[3];
    const int* srcArr = ei;
    const int* dstArr = ei + N_EDGES;

    const float *We[3], *be[3], *W1[3], *gP[3], *bP[3], *W2[3], *b2[3];
    for (int l = 0; l < 3; ++l) {
        int base = 4 + 7 * l;
        We[l] = (const float*)d_in[base + 0];
        be[l] = (const float*)d_in[base + 1];
        W1[l] = (const float*)d_in[base + 2];
        gP[l] = (const float*)d_in[base + 3];
        bP[l] = (const float*)d_in[base + 4];
        W2[l] = (const float*)d_in[base + 5];
        b2[l] = (const float*)d_in[base + 6];
    }

    char* w = (char*)d_ws;
    auto carve = [&](size_t bytes) {
        char* p = w;
        w += (bytes + 255) & ~(size_t)255;
        return p;
    };
    int* deg = (int*)carve((size_t)N_NODES * 4);
    int* rowstart = (int*)carve((size_t)(N_NODES + 1) * 4);
    int* rankArr = (int*)carve((size_t)N_EDGES * 4);
    int* bsum = (int*)carve((size_t)SCAN_NB * 4);
    int* boff = (int*)carve((size_t)SCAN_NB * 4);
    int* gstart = (int*)carve((size_t)(N_GRAPHS + 1) * 4);
    float4* adj = (float4*)carve((size_t)N_EDGES * 16);
    float* WeT1 = (float*)carve(3 * 128 * 4);
    float* WeT2 = (float*)carve(3 * 128 * 4);
    short* WF1_0 = (short*)carve(8 * 4 * 16 * 8 * 2);    // KP=32
    short* WF1_1 = (short*)carve(8 * 16 * 16 * 8 * 2);   // KP=128
    short* WF1_2 = (short*)carve(8 * 16 * 16 * 8 * 2);
    short* WF2_0 = (short*)carve(8 * 16 * 16 * 8 * 2);
    short* WF2_1 = (short*)carve(8 * 16 * 16 * 8 * 2);
    short* WF2_2 = (short*)carve(8 * 16 * 16 * 8 * 2);
    float* stats = (float*)carve(3 * 256 * 4);           // per-layer col_sum/col_sumsq
    unsigned short* xbf = (unsigned short*)carve((size_t)N_NODES * 16 * 2);
    unsigned short* y0p = (unsigned short*)carve((size_t)N_NODES * 32 * 2);
    unsigned short* hbufA = (unsigned short*)carve((size_t)N_NODES * 128 * 2);
    unsigned short* hbufB = (unsigned short*)carve((size_t)N_NODES * 128 * 2);

    hipMemsetAsync(deg, 0, (size_t)N_NODES * 4, stream);
    hipMemsetAsync(stats, 0, 3 * 256 * 4, stream);
    hipMemsetAsync(d_out, 0, (size_t)out_size * 4, stream);

    prep_k<<<(N_EDGES + 255) / 256, 256, 0, stream>>>(dstArr, deg, rankArr, x, xbf, batch, gstart,
                                                      N_EDGES, N_NODES, N_GRAPHS);
    deg_bsum_k<<<SCAN_NB, 256, 0, stream>>>(deg, bsum, N_NODES);
    bsum_scan_k<<<1, 256, 0, stream>>>(bsum, boff, rowstart, SCAN_NB, N_NODES);
    deg_scan_k<<<SCAN_NB, 256, 0, stream>>>(deg, boff, rowstart, N_NODES);
    csr_fill_k<<<(N_EDGES + 255) / 256, 256, 0, stream>>>(srcArr, dstArr, rankArr, rowstart, ea, adj, N_EDGES);

    {
        WfragArgs wa;
        wa.W[0] = W1[0]; wa.WF[0] = WF1_0; wa.din[0] = 9;   wa.KP[0] = 32;
        wa.W[1] = W1[1]; wa.WF[1] = WF1_1; wa.din[1] = 128; wa.KP[1] = 128;
        wa.W[2] = W1[2]; wa.WF[2] = WF1_2; wa.din[2] = 128; wa.KP[2] = 128;
        wa.W[3] = W2[0]; wa.WF[3] = WF2_0; wa.din[3] = 128; wa.KP[3] = 128;
        wa.W[4] = W2[1]; wa.WF[4] = WF2_1; wa.din[4] = 128; wa.KP[4] = 128;
        wa.W[5] = W2[2]; wa.WF[5] = WF2_2; wa.din[5] = 128; wa.KP[5] = 128;
        wa.We1 = We[1]; wa.We2 = We[2]; wa.WeT1 = WeT1; wa.WeT2 = WeT2;
        dim3 gw(8, 7);
        wfrag_all_k<<<gw, 256, 0, stream>>>(wa);
    }

    const int gM = (N_NODES + 127) / 128;
    const int gAgg = (N_NODES + 3) / 4;
    float* out_f = (float*)d_out;

    // ---- layer 0 (K=32 padded from din=9) ----
    agg_d9_k<<<(N_NODES + 255) / 256, 256, 0, stream>>>(xbf, rowstart, adj, We[0], be[0], y0p, N_NODES);
    mgemm1_k<32><<<gM, 256, 0, stream>>>(y0p, WF1_0, hbufB, stats, stats + 128, N_NODES);
    mgemm2_k<<<gM, 256, 0, stream>>>(hbufB, WF2_0, stats, stats + 128, gP[0], bP[0], b2[0],
                                     batch, gstart, hbufA, out_f + 0, N_NODES);

    // ---- layer 1 ----
    agg_d128_k<<<gAgg, 256, 0, stream>>>(hbufA, rowstart, adj, WeT1, be[1], hbufB, N_NODES);
    mgemm1_k<128><<<gM, 256, 0, stream>>>(hbufB, WF1_1, hbufB, stats + 256, stats + 384, N_NODES);
    mgemm2_k<<<gM, 256, 0, stream>>>(hbufB, WF2_1, stats + 256, stats + 384, gP[1], bP[1], b2[1],
                                     batch, gstart, hbufA, out_f + 128, N_NODES);

    // ---- layer 2 ----
    agg_d128_k<<<gAgg, 256, 0, stream>>>(hbufA, rowstart, adj, WeT2, be[2], hbufB, N_NODES);
    mgemm1_k<128><<<gM, 256, 0, stream>>>(hbufB, WF1_2, hbufB, stats + 512, stats + 640, N_NODES);
    mgemm2_k<<<gM, 256, 0, stream>>>(hbufB, WF2_2, stats + 512, stats + 640, gP[2], bP[2], b2[2],
                                     batch, gstart, nullptr, out_f + 256, N_NODES);
}

// Round 13
// 410.114 us; speedup vs baseline: 1.0925x; 1.0158x over previous
//
#include <hip/hip_runtime.h>

#define N_NODES 50000
#define N_EDGES 800000
#define N_GRAPHS 500
#define DH 128
#define OUT_STRIDE 384
#define BN_EPS 1e-5f
#define SCAN_NB ((N_NODES + 255) / 256)

typedef __attribute__((ext_vector_type(8))) short bf16x8;
typedef __attribute__((ext_vector_type(4))) float f32x4;

__device__ __forceinline__ float4 ld4(const float* p) { return *(const float4*)p; }
__device__ __forceinline__ void st4(float* p, float4 v) { *(float4*)p = v; }

__device__ __forceinline__ short f2bf(float f) {
    union { float f; unsigned u; } v; v.f = f;
    unsigned r = v.u + 0x7FFFu + ((v.u >> 16) & 1u);
    return (short)(r >> 16);
}
__device__ __forceinline__ float bu2f(unsigned short v) {
    union { unsigned u; float f; } x; x.u = ((unsigned)v) << 16; return x.f;
}
__device__ __forceinline__ float blo(int w) {
    union { unsigned u; float f; } x; x.u = ((unsigned)w) << 16; return x.f;
}
__device__ __forceinline__ float bhi(int w) {
    union { unsigned u; float f; } x; x.u = (unsigned)w & 0xFFFF0000u; return x.f;
}

// ---------------- fused prep: deg count + edge rank (edge) + x->bf16[16] + graph bounds (node) ----------------
__global__ void prep_k(const int* __restrict__ dst, int* __restrict__ deg,
                       int* __restrict__ rankArr,
                       const float* __restrict__ x, unsigned short* __restrict__ xbf,
                       const int* __restrict__ batch, int* __restrict__ gstart,
                       int E, int n, int G) {
    int i = blockIdx.x * 256 + threadIdx.x;
    if (i < E) rankArr[i] = atomicAdd(&deg[dst[i]], 1);
    if (i < n) {
        const float* s = x + (size_t)i * 9;
        union { unsigned short u[16]; int4 v[2]; } o;
#pragma unroll
        for (int j = 0; j < 9; ++j) o.u[j] = (unsigned short)f2bf(s[j]);
#pragma unroll
        for (int j = 9; j < 16; ++j) o.u[j] = 0;
        int4* d = (int4*)(xbf + (size_t)i * 16);
        d[0] = o.v[0];
        d[1] = o.v[1];
        int b = batch[i];
        if (i == 0) {
            for (int g = 0; g <= b; ++g) gstart[g] = 0;
        } else {
            int p = batch[i - 1];
            for (int g = p + 1; g <= b; ++g) gstart[g] = i;
        }
        if (i == n - 1) {
            for (int g = b + 1; g <= G; ++g) gstart[g] = n;
        }
    }
}

// hierarchical scan
__global__ void deg_bsum_k(const int* __restrict__ deg, int* __restrict__ bsum, int n) {
    __shared__ int red[256];
    int t = threadIdx.x, i = blockIdx.x * 256 + t;
    red[t] = (i < n) ? deg[i] : 0;
    __syncthreads();
    for (int off = 128; off > 0; off >>= 1) {
        if (t < off) red[t] += red[t + off];
        __syncthreads();
    }
    if (t == 0) bsum[blockIdx.x] = red[0];
}

__global__ void bsum_scan_k(const int* __restrict__ bsum, int* __restrict__ boff,
                            int* __restrict__ rowstart, int nb, int n) {
    __shared__ int s[256];
    int t = threadIdx.x;
    int v = (t < nb) ? bsum[t] : 0;
    s[t] = v;
    __syncthreads();
    for (int off = 1; off < 256; off <<= 1) {
        int u = (t >= off) ? s[t - off] : 0;
        __syncthreads();
        s[t] += u;
        __syncthreads();
    }
    if (t < nb) boff[t] = s[t] - v;
    if (t == 255) rowstart[n] = s[255];
}

__global__ void deg_scan_k(const int* __restrict__ deg, const int* __restrict__ boff,
                           int* __restrict__ rowstart, int n) {
    __shared__ int s[256];
    int t = threadIdx.x, i = blockIdx.x * 256 + t;
    int v = (i < n) ? deg[i] : 0;
    s[t] = v;
    __syncthreads();
    for (int off = 1; off < 256; off <<= 1) {
        int u = (t >= off) ? s[t - off] : 0;
        __syncthreads();
        s[t] += u;
        __syncthreads();
    }
    if (i < n) rowstart[i] = boff[blockIdx.x] + s[t] - v;
}

// atomic-free CSR fill: pos = rowstart[dst] + precomputed rank. 16B record {src, e0,e1,e2}.
__global__ void csr_fill_k(const int* __restrict__ src, const int* __restrict__ dst,
                           const int* __restrict__ rankArr, const int* __restrict__ rowstart,
                           const float* __restrict__ ea, float4* __restrict__ adj, int E) {
    int e = blockIdx.x * 256 + threadIdx.x;
    if (e >= E) return;
    int pos = rowstart[dst[e]] + rankArr[e];
    adj[pos] = make_float4(__int_as_float(src[e]), ea[e * 3 + 0], ea[e * 3 + 1], ea[e * 3 + 2]);
}

// ---------------- W -> bf16 MFMA B-frags (+ We transposes in slot y==6) ----------------
struct WfragArgs {
    const float* W[6];
    short* WF[6];
    int din[6];
    int KP[6];
    const float* We1;
    const float* We2;
    float* WeT1;
    float* WeT2;
};

__global__ void wfrag_all_k(WfragArgs a) {
    int which = blockIdx.y;
    int idx = blockIdx.x * 256 + threadIdx.x;
    if (which == 6) {
        if (idx < 384) {
            int r = idx / 3, c = idx - r * 3;
            a.WeT1[c * 128 + r] = a.We1[idx];
        } else if (idx < 768) {
            int j = idx - 384;
            int r = j / 3, c = j - r * 3;
            a.WeT2[c * 128 + r] = a.We2[j];
        }
        return;
    }
    int din = a.din[which], KP = a.KP[which];
    const float* W = a.W[which];
    short* WF = a.WF[which];
    int NC = KP >> 3;
    int total = 8 * NC * 16;
    if (idx >= total) return;
    int n16 = idx & 15;
    int rest = idx >> 4;
    int c = rest % NC;
    int nt = rest / NC;
    int n = nt * 16 + n16;
    union { short s[8]; int4 v; } u;
#pragma unroll
    for (int j = 0; j < 8; ++j) {
        int k = c * 8 + j;
        float val = (k < din) ? W[(size_t)n * din + k] : 0.f;
        u.s[j] = f2bf(val);
    }
    ((int4*)WF)[idx] = u.v;
}

// ---------------- aggregation layer 0: y_bf16[n][32] = pad(x + sum relu(x[src]+Lin(ea))) ----------------
__global__ __launch_bounds__(256) void agg_d9_k(
    const unsigned short* __restrict__ xbf /*[n][16] bf16*/, const int* __restrict__ rowstart,
    const float4* __restrict__ adj,
    const float* __restrict__ We /*[9][3]*/, const float* __restrict__ be,
    unsigned short* __restrict__ y /*[n][32] bf16*/, int n) {
    int i = blockIdx.x * 256 + threadIdx.x;
    if (i >= n) return;
    float w0[9], w1[9], w2[9], bb[9], acc[9];
#pragma unroll
    for (int j = 0; j < 9; ++j) {
        w0[j] = We[j * 3 + 0];
        w1[j] = We[j * 3 + 1];
        w2[j] = We[j * 3 + 2];
        bb[j] = be[j];
    }
    {
        const int4* xr4 = (const int4*)(xbf + (size_t)i * 16);
        int4 a = xr4[0];
        int w8 = ((const int*)xbf)[(size_t)i * 8 + 4];
        acc[0] = blo(a.x); acc[1] = bhi(a.x);
        acc[2] = blo(a.y); acc[3] = bhi(a.y);
        acc[4] = blo(a.z); acc[5] = bhi(a.z);
        acc[6] = blo(a.w); acc[7] = bhi(a.w);
        acc[8] = blo(w8);
    }
    int k1 = rowstart[i + 1];
    for (int k = rowstart[i]; k < k1; ++k) {
        float4 ed = adj[k];
        int s = __float_as_int(ed.x);
        float e0 = ed.y, e1 = ed.z, e2 = ed.w;
        int4 a = *(const int4*)(xbf + (size_t)s * 16);
        int w8 = ((const int*)xbf)[(size_t)s * 8 + 4];
        float xv[9] = {blo(a.x), bhi(a.x), blo(a.y), bhi(a.y),
                       blo(a.z), bhi(a.z), blo(a.w), bhi(a.w), blo(w8)};
#pragma unroll
        for (int j = 0; j < 9; ++j) {
            float lin = fmaf(w0[j], e0, fmaf(w1[j], e1, fmaf(w2[j], e2, bb[j])));
            acc[j] += fmaxf(xv[j] + lin, 0.f);
        }
    }
    union { unsigned short s[32]; int4 v[4]; } u;
#pragma unroll
    for (int j = 0; j < 9; ++j) u.s[j] = (unsigned short)f2bf(acc[j]);
#pragma unroll
    for (int j = 9; j < 32; ++j) u.s[j] = 0;
    int4* yp = (int4*)(y + (size_t)i * 32);
#pragma unroll
    for (int j = 0; j < 4; ++j) yp[j] = u.v[j];
}

// ---------------- aggregation d=128: one wave/node, edge-halves, 4-deep ILP; bf16 h in/out ----------------
__global__ __launch_bounds__(256) void agg_d128_k(
    const unsigned short* __restrict__ hbf, const int* __restrict__ rowstart,
    const float4* __restrict__ adj,
    const float* __restrict__ WeT /*[3][128]*/, const float* __restrict__ be,
    unsigned short* __restrict__ y /*[n][128] bf16*/, int n) {
    int lane = threadIdx.x & 63;
    int node = blockIdx.x * 4 + (threadIdx.x >> 6);
    if (node >= n) return;
    int l31 = lane & 31, half = lane >> 5;
    int c = l31 * 4;
    float4 w0 = ld4(&WeT[0 * 128 + c]);
    float4 w1 = ld4(&WeT[1 * 128 + c]);
    float4 w2 = ld4(&WeT[2 * 128 + c]);
    float4 b4 = ld4(&be[c]);
    float4 acc = make_float4(0.f, 0.f, 0.f, 0.f);
    const ushort4* hb = (const ushort4*)hbf;
    int k1 = rowstart[node + 1];
    int k = rowstart[node] + half;
    for (; k + 6 < k1; k += 8) {
        float4 e[4] = {adj[k], adj[k + 2], adj[k + 4], adj[k + 6]};
        ushort4 u[4];
#pragma unroll
        for (int j = 0; j < 4; ++j) u[j] = hb[(size_t)__float_as_int(e[j].x) * 32 + l31];
#pragma unroll
        for (int j = 0; j < 4; ++j) {
            float e0 = e[j].y, e1 = e[j].z, e2 = e[j].w;
            acc.x += fmaxf(fmaf(w0.x, e0, fmaf(w1.x, e1, fmaf(w2.x, e2, b4.x))) + bu2f(u[j].x), 0.f);
            acc.y += fmaxf(fmaf(w0.y, e0, fmaf(w1.y, e1, fmaf(w2.y, e2, b4.y))) + bu2f(u[j].y), 0.f);
            acc.z += fmaxf(fmaf(w0.z, e0, fmaf(w1.z, e1, fmaf(w2.z, e2, b4.z))) + bu2f(u[j].z), 0.f);
            acc.w += fmaxf(fmaf(w0.w, e0, fmaf(w1.w, e1, fmaf(w2.w, e2, b4.w))) + bu2f(u[j].w), 0.f);
        }
    }
    for (; k < k1; k += 2) {
        float4 ed = adj[k];
        int s = __float_as_int(ed.x);
        float e0 = ed.y, e1 = ed.z, e2 = ed.w;
        ushort4 ua = hb[(size_t)s * 32 + l31];
        acc.x += fmaxf(fmaf(w0.x, e0, fmaf(w1.x, e1, fmaf(w2.x, e2, b4.x))) + bu2f(ua.x), 0.f);
        acc.y += fmaxf(fmaf(w0.y, e0, fmaf(w1.y, e1, fmaf(w2.y, e2, b4.y))) + bu2f(ua.y), 0.f);
        acc.z += fmaxf(fmaf(w0.z, e0, fmaf(w1.z, e1, fmaf(w2.z, e2, b4.z))) + bu2f(ua.z), 0.f);
        acc.w += fmaxf(fmaf(w0.w, e0, fmaf(w1.w, e1, fmaf(w2.w, e2, b4.w))) + bu2f(ua.w), 0.f);
    }
    acc.x += __shfl_xor(acc.x, 32);
    acc.y += __shfl_xor(acc.y, 32);
    acc.z += __shfl_xor(acc.z, 32);
    acc.w += __shfl_xor(acc.w, 32);
    if (half == 0) {
        ushort4 xv = hb[(size_t)node * 32 + l31];
        ushort4 o;
        o.x = (unsigned short)f2bf(acc.x + bu2f(xv.x));
        o.y = (unsigned short)f2bf(acc.y + bu2f(xv.y));
        o.z = (unsigned short)f2bf(acc.z + bu2f(xv.z));
        o.w = (unsigned short)f2bf(acc.w + bu2f(xv.w));
        ((ushort4*)y)[(size_t)node * 32 + l31] = o;
    }
}

// ---------------- A-fragment helpers ----------------
__device__ __forceinline__ bf16x8 loadAbf(const unsigned short* p, bool v) {
    if (v) return *(const bf16x8*)p;
    bf16x8 z = {0, 0, 0, 0, 0, 0, 0, 0};
    return z;
}

__device__ __forceinline__ bf16x8 loadA_bn(const unsigned short* p, bool v,
                                           float4 sc0, float4 sc1, float4 sh0, float4 sh1) {
    union { short s[8]; bf16x8 v8; } u;
    if (v) {
        union { ushort4 q[2]; unsigned short s[8]; } iv;
        iv.q[0] = *(const ushort4*)p;
        iv.q[1] = *(const ushort4*)(p + 4);
        u.s[0] = f2bf(fmaxf(fmaf(bu2f(iv.s[0]), sc0.x, sh0.x), 0.f));
        u.s[1] = f2bf(fmaxf(fmaf(bu2f(iv.s[1]), sc0.y, sh0.y), 0.f));
        u.s[2] = f2bf(fmaxf(fmaf(bu2f(iv.s[2]), sc0.z, sh0.z), 0.f));
        u.s[3] = f2bf(fmaxf(fmaf(bu2f(iv.s[3]), sc0.w, sh0.w), 0.f));
        u.s[4] = f2bf(fmaxf(fmaf(bu2f(iv.s[4]), sc1.x, sh1.x), 0.f));
        u.s[5] = f2bf(fmaxf(fmaf(bu2f(iv.s[5]), sc1.y, sh1.y), 0.f));
        u.s[6] = f2bf(fmaxf(fmaf(bu2f(iv.s[6]), sc1.z, sh1.z), 0.f));
        u.s[7] = f2bf(fmaxf(fmaf(bu2f(iv.s[7]), sc1.w, sh1.w), 0.f));
    } else {
#pragma unroll
        for (int j = 0; j < 8; ++j) u.s[j] = 0;
    }
    return u.v8;
}

// ---------------- MFMA GEMM1 (column-split): block = 64 rows x 128 cols, 4 waves ----------------
// wave w: rowgroup rg2=w&1 (32 rows), col-half ch=w>>1 (64 cols). 2x grid vs 128-row version
// -> ~3 waves/SIMD for latency hiding.
template <int KP>
__global__ __launch_bounds__(256) void mgemm1_k(
    const unsigned short* Y /* [n][KP] bf16 */, const short* __restrict__ WF,
    unsigned short* Hout /* [n][128] bf16 */, float* __restrict__ col_sum,
    float* __restrict__ col_sumsq, int n) {
    constexpr int NC = KP / 8;
    constexpr int KB = KP / 32;
    __shared__ short Wlds[8 * NC * 16 * 8];
    __shared__ float red[256];
    const int t = threadIdx.x;
    const int lane = t & 63, w = t >> 6;
    const int l15 = lane & 15, q = lane >> 4;
    const int rg2 = w & 1, ch = w >> 1;
    const int row0 = blockIdx.x * 64 + rg2 * 32;

    {
        const int4* s = (const int4*)WF;
        int4* d = (int4*)Wlds;
        for (int i = t; i < 8 * NC * 16; i += 256) d[i] = s[i];
    }
    red[t] = 0.f;
    __syncthreads();

    f32x4 acc[2][4];
#pragma unroll
    for (int rt = 0; rt < 2; ++rt)
#pragma unroll
        for (int nt = 0; nt < 4; ++nt) acc[rt][nt] = (f32x4){0.f, 0.f, 0.f, 0.f};

    const int r0 = row0 + l15, r1 = row0 + 16 + l15;
    const unsigned short* p0 = Y + (size_t)r0 * KP + q * 8;
    const unsigned short* p1 = Y + (size_t)r1 * KP + q * 8;
    const bool v0 = r0 < n, v1 = r1 < n;
    const bf16x8* WL = (const bf16x8*)Wlds;

#pragma unroll
    for (int b = 0; b < KB; ++b) {
        bf16x8 a0 = loadAbf(p0 + b * 32, v0);
        bf16x8 a1 = loadAbf(p1 + b * 32, v1);
#pragma unroll
        for (int nt = 0; nt < 4; ++nt) {
            bf16x8 bf = WL[((ch * 4 + nt) * NC + b * 4 + q) * 16 + l15];
            acc[0][nt] = __builtin_amdgcn_mfma_f32_16x16x32_bf16(a0, bf, acc[0][nt], 0, 0, 0);
            acc[1][nt] = __builtin_amdgcn_mfma_f32_16x16x32_bf16(a1, bf, acc[1][nt], 0, 0, 0);
        }
    }

#pragma unroll
    for (int nt = 0; nt < 4; ++nt) {
        const int cidx = ch * 64 + nt * 16 + l15;
        float s = 0.f, ss = 0.f;
#pragma unroll
        for (int rt = 0; rt < 2; ++rt) {
            int rb = row0 + rt * 16 + q * 4;
#pragma unroll
            for (int i = 0; i < 4; ++i) {
                float d = acc[rt][nt][i];
                int r = rb + i;
                if (r < n) Hout[(size_t)r * 128 + cidx] = (unsigned short)f2bf(d);
                s += d;
                ss += d * d;
            }
        }
        s += __shfl_xor(s, 16);
        s += __shfl_xor(s, 32);
        ss += __shfl_xor(ss, 16);
        ss += __shfl_xor(ss, 32);
        if (lane < 16) {
            atomicAdd(&red[cidx], s);
            atomicAdd(&red[128 + cidx], ss);
        }
    }
    __syncthreads();
    if (t < 128) atomicAdd(&col_sum[t], red[t]);
    else atomicAdd(&col_sumsq[t - 128], red[t]);
}

// ---------------- MFMA GEMM2 (column-split, fused BN finalize + bias/relu + graph pool) ----------------
__global__ __launch_bounds__(256) void mgemm2_k(
    const unsigned short* Hpre /* bf16 */, const short* __restrict__ WF,
    const float* __restrict__ col_sum, const float* __restrict__ col_sumsq,
    const float* __restrict__ gw, const float* __restrict__ bw,
    const float* __restrict__ bias,
    const int* __restrict__ batch, const int* __restrict__ gstart,
    unsigned short* __restrict__ Hbf /* bf16 out, may be null */,
    float* __restrict__ outp, int n) {
    constexpr int NC = 16;
    __shared__ __align__(16) char smem[64 * 132 * 4];  // union: Wlds (32 KB) / Llds (33 KB)
    __shared__ float scsh[256];
    short* Wlds = (short*)smem;
    float* Llds = (float*)smem;
    const int t = threadIdx.x;
    const int lane = t & 63, w = t >> 6;
    const int l15 = lane & 15, q = lane >> 4;
    const int rg2 = w & 1, ch = w >> 1;
    const int row0 = blockIdx.x * 64 + rg2 * 32;

    {
        const int4* s = (const int4*)WF;
        int4* d = (int4*)Wlds;
        for (int i = t; i < 8 * NC * 16; i += 256) d[i] = s[i];
    }
    if (t < 128) {
        float inv_n = 1.0f / (float)n;
        float mean = col_sum[t] * inv_n;
        float var = col_sumsq[t] * inv_n - mean * mean;
        float a = gw[t] * rsqrtf(var + BN_EPS);
        scsh[t] = a;
        scsh[128 + t] = fmaf(-mean, a, bw[t]);
    }
    __syncthreads();

    f32x4 acc[2][4];
#pragma unroll
    for (int rt = 0; rt < 2; ++rt)
#pragma unroll
        for (int nt = 0; nt < 4; ++nt) acc[rt][nt] = (f32x4){0.f, 0.f, 0.f, 0.f};

    const int r0 = row0 + l15, r1 = row0 + 16 + l15;
    const unsigned short* p0 = Hpre + (size_t)r0 * 128 + q * 8;
    const unsigned short* p1 = Hpre + (size_t)r1 * 128 + q * 8;
    const bool v0 = r0 < n, v1 = r1 < n;
    const bf16x8* WL = (const bf16x8*)Wlds;

#pragma unroll
    for (int b = 0; b < 4; ++b) {
        const int k0 = b * 32 + q * 8;
        float4 sc0 = ld4(&scsh[k0]), sc1 = ld4(&scsh[k0 + 4]);
        float4 sh0 = ld4(&scsh[128 + k0]), sh1 = ld4(&scsh[128 + k0 + 4]);
        bf16x8 a0 = loadA_bn(p0 + b * 32, v0, sc0, sc1, sh0, sh1);
        bf16x8 a1 = loadA_bn(p1 + b * 32, v1, sc0, sc1, sh0, sh1);
#pragma unroll
        for (int nt = 0; nt < 4; ++nt) {
            bf16x8 bf = WL[((ch * 4 + nt) * NC + b * 4 + q) * 16 + l15];
            acc[0][nt] = __builtin_amdgcn_mfma_f32_16x16x32_bf16(a0, bf, acc[0][nt], 0, 0, 0);
            acc[1][nt] = __builtin_amdgcn_mfma_f32_16x16x32_bf16(a1, bf, acc[1][nt], 0, 0, 0);
        }
    }

    __syncthreads();  // all waves done with Wlds before overwrite

    const int r0w = blockIdx.x * 64;
#pragma unroll
    for (int nt = 0; nt < 4; ++nt) {
        const int cidx = ch * 64 + nt * 16 + l15;
        float bcol = bias[cidx];
#pragma unroll
        for (int rt = 0; rt < 2; ++rt) {
            int rb = row0 + rt * 16 + q * 4;
#pragma unroll
            for (int i = 0; i < 4; ++i) {
                int r = rb + i;
                float o = 0.f;
                if (r < n) {
                    o = fmaxf(acc[rt][nt][i] + bcol, 0.f);
                    if (Hbf) Hbf[(size_t)r * 128 + cidx] = (unsigned short)f2bf(o);
                }
                Llds[(r - r0w) * 132 + cidx] = o;
            }
        }
    }
    __syncthreads();
    if (r0w < n) {
        int c = t & 127, half = t >> 7;
        int g = batch[r0w];
        while (g < N_GRAPHS) {
            int segs = max(gstart[g], r0w);
            int sege = min(gstart[g + 1], r0w + 64);
            if (segs >= r0w + 64) break;
            float s = 0.f;
            for (int r = segs + half; r < sege; r += 2) s += Llds[(r - r0w) * 132 + c];
            if (s != 0.f) atomicAdd(&outp[(size_t)g * OUT_STRIDE + c], s);
            if (gstart[g + 1] >= r0w + 64) break;
            ++g;
        }
    }
}

extern "C" void kernel_launch(void* const* d_in, const int* in_sizes, int n_in,
                              void* d_out, int out_size, void* d_ws, size_t ws_size,
                              hipStream_t stream) {
    const float* x = (const float*)d_in[0];
    const int* ei = (const int*)d_in[1];
    const float* ea = (const float*)d_in[2];
    const int* batch = (const int*)d_in[3];
    const int* srcArr = ei;
    const int* dstArr = ei + N_EDGES;

    const float *We[3], *be[3], *W1[3], *gP[3], *bP[3], *W2[3], *b2[3];
    for (int l = 0; l < 3; ++l) {
        int base = 4 + 7 * l;
        We[l] = (const float*)d_in[base + 0];
        be[l] = (const float*)d_in[base + 1];
        W1[l] = (const float*)d_in[base + 2];
        gP[l] = (const float*)d_in[base + 3];
        bP[l] = (const float*)d_in[base + 4];
        W2[l] = (const float*)d_in[base + 5];
        b2[l] = (const float*)d_in[base + 6];
    }

    char* w = (char*)d_ws;
    auto carve = [&](size_t bytes) {
        char* p = w;
        w += (bytes + 255) & ~(size_t)255;
        return p;
    };
    int* deg = (int*)carve((size_t)N_NODES * 4);
    int* rowstart = (int*)carve((size_t)(N_NODES + 1) * 4);
    int* rankArr = (int*)carve((size_t)N_EDGES * 4);
    int* bsum = (int*)carve((size_t)SCAN_NB * 4);
    int* boff = (int*)carve((size_t)SCAN_NB * 4);
    int* gstart = (int*)carve((size_t)(N_GRAPHS + 1) * 4);
    float4* adj = (float4*)carve((size_t)N_EDGES * 16);
    float* WeT1 = (float*)carve(3 * 128 * 4);
    float* WeT2 = (float*)carve(3 * 128 * 4);
    short* WF1_0 = (short*)carve(8 * 4 * 16 * 8 * 2);    // KP=32
    short* WF1_1 = (short*)carve(8 * 16 * 16 * 8 * 2);   // KP=128
    short* WF1_2 = (short*)carve(8 * 16 * 16 * 8 * 2);
    short* WF2_0 = (short*)carve(8 * 16 * 16 * 8 * 2);
    short* WF2_1 = (short*)carve(8 * 16 * 16 * 8 * 2);
    short* WF2_2 = (short*)carve(8 * 16 * 16 * 8 * 2);
    float* stats = (float*)carve(3 * 256 * 4);           // per-layer col_sum/col_sumsq
    unsigned short* xbf = (unsigned short*)carve((size_t)N_NODES * 16 * 2);
    unsigned short* y0p = (unsigned short*)carve((size_t)N_NODES * 32 * 2);
    unsigned short* hbufA = (unsigned short*)carve((size_t)N_NODES * 128 * 2);
    unsigned short* hbufB = (unsigned short*)carve((size_t)N_NODES * 128 * 2);

    hipMemsetAsync(deg, 0, (size_t)N_NODES * 4, stream);
    hipMemsetAsync(stats, 0, 3 * 256 * 4, stream);
    hipMemsetAsync(d_out, 0, (size_t)out_size * 4, stream);

    prep_k<<<(N_EDGES + 255) / 256, 256, 0, stream>>>(dstArr, deg, rankArr, x, xbf, batch, gstart,
                                                      N_EDGES, N_NODES, N_GRAPHS);
    deg_bsum_k<<<SCAN_NB, 256, 0, stream>>>(deg, bsum, N_NODES);
    bsum_scan_k<<<1, 256, 0, stream>>>(bsum, boff, rowstart, SCAN_NB, N_NODES);
    deg_scan_k<<<SCAN_NB, 256, 0, stream>>>(deg, boff, rowstart, N_NODES);
    csr_fill_k<<<(N_EDGES + 255) / 256, 256, 0, stream>>>(srcArr, dstArr, rankArr, rowstart, ea, adj, N_EDGES);

    {
        WfragArgs wa;
        wa.W[0] = W1[0]; wa.WF[0] = WF1_0; wa.din[0] = 9;   wa.KP[0] = 32;
        wa.W[1] = W1[1]; wa.WF[1] = WF1_1; wa.din[1] = 128; wa.KP[1] = 128;
        wa.W[2] = W1[2]; wa.WF[2] = WF1_2; wa.din[2] = 128; wa.KP[2] = 128;
        wa.W[3] = W2[0]; wa.WF[3] = WF2_0; wa.din[3] = 128; wa.KP[3] = 128;
        wa.W[4] = W2[1]; wa.WF[4] = WF2_1; wa.din[4] = 128; wa.KP[4] = 128;
        wa.W[5] = W2[2]; wa.WF[5] = WF2_2; wa.din[5] = 128; wa.KP[5] = 128;
        wa.We1 = We[1]; wa.We2 = We[2]; wa.WeT1 = WeT1; wa.WeT2 = WeT2;
        dim3 gw(8, 7);
        wfrag_all_k<<<gw, 256, 0, stream>>>(wa);
    }

    const int gM = (N_NODES + 63) / 64;
    const int gAgg = (N_NODES + 3) / 4;
    float* out_f = (float*)d_out;

    // ---- layer 0 (K=32 padded from din=9) ----
    agg_d9_k<<<(N_NODES + 255) / 256, 256, 0, stream>>>(xbf, rowstart, adj, We[0], be[0], y0p, N_NODES);
    mgemm1_k<32><<<gM, 256, 0, stream>>>(y0p, WF1_0, hbufB, stats, stats + 128, N_NODES);
    mgemm2_k<<<gM, 256, 0, stream>>>(hbufB, WF2_0, stats, stats + 128, gP[0], bP[0], b2[0],
                                     batch, gstart, hbufA, out_f + 0, N_NODES);

    // ---- layer 1 ----
    agg_d128_k<<<gAgg, 256, 0, stream>>>(hbufA, rowstart, adj, WeT1, be[1], hbufB, N_NODES);
    mgemm1_k<128><<<gM, 256, 0, stream>>>(hbufB, WF1_1, hbufB, stats + 256, stats + 384, N_NODES);
    mgemm2_k<<<gM, 256, 0, stream>>>(hbufB, WF2_1, stats + 256, stats + 384, gP[1], bP[1], b2[1],
                                     batch, gstart, hbufA, out_f + 128, N_NODES);

    // ---- layer 2 ----
    agg_d128_k<<<gAgg, 256, 0, stream>>>(hbufA, rowstart, adj, WeT2, be[2], hbufB, N_NODES);
    mgemm1_k<128><<<gM, 256, 0, stream>>>(hbufB, WF1_2, hbufB, stats + 512, stats + 640, N_NODES);
    mgemm2_k<<<gM, 256, 0, stream>>>(hbufB, WF2_2, stats + 512, stats + 640, gP[2], bP[2], b2[2],
                                     batch, gstart, nullptr, out_f + 256, N_NODES);
}